// Round 8
// baseline (2287.948 us; speedup 1.0000x reference)
//
#include <hip/hip_runtime.h>
#include <hip/hip_bf16.h>
#include <stdint.h>
#include <type_traits>

// Bidirectional 2-layer LSTM, B=32, T=2048, F=H=128, G=4H=512.
// prep (Wx,Wh -> scaled bf16 frags) -> proj L0 -> scan L0 (16 WGs: dir x 8
// batch-octants of 4 rows) -> proj L1 -> scan L1. Gate pre-activations are
// pre-scaled by -log2e (i,f,o) / -2log2e (g) so sigmoid = rcp(1+exp2(y)).
// 7-trans common-denominator activation; 1 state elem per lane (consecutive
// row-dup: A row m = real row m>>2 so lane-group p's acc[0] = real row p).
// R8: gx folded into MFMA C-operand (persistent C-quads, elems 1-3 = 0);
// ks0-warmup MFMA order hides ds_read latency; per-gate exp2 issued right
// after each gate's chain so trans overlap the remaining MFMAs.

#define DEVINL __device__ __forceinline__

typedef __attribute__((ext_vector_type(8))) short short8;
typedef __attribute__((ext_vector_type(4))) float f32x4;

static constexpr int T = 2048;
static constexpr size_t XOUT = (size_t)32 * T * 256;
static constexpr float L2E = 1.4426950408889634f;
static constexpr float M2L2E = -2.8853900817779268f;

DEVINL unsigned short f2bf(float f) {
  unsigned int u = __float_as_uint(f);
  u += 0x7FFFu + ((u >> 16) & 1u);  // RNE
  return (unsigned short)(u >> 16);
}
DEVINL float gate_scale(int g) { return (g == 2) ? M2L2E : -L2E; }

// ---------------------------------------------------------------------------
// prep_wx: Wx (f32 [K][512]) -> scaled bf16 B-frags [dir][ng(32)][ks][lane][e8]
// ---------------------------------------------------------------------------
__global__ __launch_bounds__(256) void prep_wx(const float* wxf0, const float* wxb0,
                                               const float* wxf1, const float* wxb1,
                                               unsigned short* sw0, unsigned short* sw1) {
  int idx = blockIdx.x * 256 + threadIdx.x;
  if (idx < 2 * 65536) {                       // layer 0, KS=4
    int d = idx >> 16;
    int local = idx & 65535;
    const float* w = d ? wxb0 : wxf0;
    int e = local & 7, lane = (local >> 3) & 63, ks = (local >> 9) & 3, ng = local >> 11;
    int col = ng * 16 + (lane & 15);
    int k = ks * 32 + ((lane >> 4) << 3) + e;
    sw0[idx] = f2bf(w[k * 512 + col] * gate_scale(ng >> 3));
  } else {                                     // layer 1, KS=8
    int j = idx - 2 * 65536;
    if (j < 2 * 131072) {
      int d = j >> 17;
      int local = j & 131071;
      const float* w = d ? wxb1 : wxf1;
      int e = local & 7, lane = (local >> 3) & 63, ks = (local >> 9) & 7, ng = local >> 12;
      int col = ng * 16 + (lane & 15);
      int k = ks * 32 + ((lane >> 4) << 3) + e;
      sw1[j] = f2bf(w[k * 512 + col] * gate_scale(ng >> 3));
    }
  }
}

// ---------------------------------------------------------------------------
// prep_wh: Wh (f32 [128][512]) -> scaled bf16 frags, contiguous per wave:
// idx bits: e(0-2) lane(3-8) wid(9-11) ks(12-13) g(14-15) dir(16) layer(17)
// ---------------------------------------------------------------------------
__global__ __launch_bounds__(256) void prep_wh(const float* whf0, const float* whb0,
                                               const float* whf1, const float* whb1,
                                               unsigned short* swh) {
  int idx = blockIdx.x * 256 + threadIdx.x;
  if (idx >= 262144) return;
  int e = idx & 7, lane = (idx >> 3) & 63, wid = (idx >> 9) & 7;
  int ks = (idx >> 12) & 3, g = (idx >> 14) & 3, dir = (idx >> 16) & 1, layer = (idx >> 17) & 1;
  const float* w = layer ? (dir ? whb1 : whf1) : (dir ? whb0 : whf0);
  int col = g * 128 + wid * 16 + (lane & 15);
  int k = ks * 32 + ((lane >> 4) << 3) + e;
  swh[idx] = f2bf(w[k * 512 + col] * gate_scale(g));
}

// ---------------------------------------------------------------------------
// input_proj: xp[dir][t][q(8)][row(4)][col(128)][g(4)] = A(t)@Wx_scaled + b.
// Scan thread (q, row=p, col) then loads ONE float4/uint2 (4 gates).
// ---------------------------------------------------------------------------
template <int LAYER, bool XPF32>
__global__ __launch_bounds__(256) void input_proj(const float* x, const unsigned short* a_bf,
                                                  const unsigned short* wsw,
                                                  const float* bias_f, const float* bias_b,
                                                  void* xp_out) {
  constexpr int KS = (LAYER == 0) ? 4 : 8;
  int t = blockIdx.x, dir = blockIdx.y;
  int wid = threadIdx.x >> 6, lane = threadIdx.x & 63;   // wid = 0..3
  int p = lane >> 4, c15 = lane & 15;
  const unsigned short* wbase = wsw + (size_t)dir * (32 * KS * 64 * 8);
  const float* bias = dir ? bias_b : bias_f;

  short8 afrag[2][KS];
#pragma unroll
  for (int mt = 0; mt < 2; ++mt) {
#pragma unroll
    for (int ks = 0; ks < KS; ++ks) {
      int m = c15 + mt * 16;
      int kk = ks * 32 + (p << 3);
      if constexpr (LAYER == 0) {
        const float* ap = x + (size_t)m * (T * 128) + (size_t)t * 128 + kk;
        float4 lov = *(const float4*)ap;
        float4 hiv = *(const float4*)(ap + 4);
        short8 s;
        s[0] = (short)f2bf(lov.x); s[1] = (short)f2bf(lov.y);
        s[2] = (short)f2bf(lov.z); s[3] = (short)f2bf(lov.w);
        s[4] = (short)f2bf(hiv.x); s[5] = (short)f2bf(hiv.y);
        s[6] = (short)f2bf(hiv.z); s[7] = (short)f2bf(hiv.w);
        afrag[mt][ks] = s;
      } else {
        afrag[mt][ks] = *(const short8*)(a_bf + ((size_t)t * 32 + m) * 256 + kk);
      }
    }
  }

#pragma unroll
  for (int ngi = 0; ngi < 8; ++ngi) {
    int ng = wid * 8 + ngi;
    int g = ng >> 3, wd = ng & 7;
    f32x4 acc0 = {0.f, 0.f, 0.f, 0.f};
    f32x4 acc1 = {0.f, 0.f, 0.f, 0.f};
#pragma unroll
    for (int ks = 0; ks < KS; ++ks) {
      short8 b = *(const short8*)(wbase + ((size_t)(ng * KS + ks) * 64 + lane) * 8);
      acc0 = __builtin_amdgcn_mfma_f32_16x16x32_bf16(afrag[0][ks], b, acc0, 0, 0, 0);
      acc1 = __builtin_amdgcn_mfma_f32_16x16x32_bf16(afrag[1][ks], b, acc1, 0, 0, 0);
    }
    float bs = bias[ng * 16 + c15] * gate_scale(g);
    int gcol = wd * 16 + c15;
#pragma unroll
    for (int mt = 0; mt < 2; ++mt) {
      f32x4 v = (mt == 0) ? acc0 : acc1;
      v[0] += bs; v[1] += bs; v[2] += bs; v[3] += bs;
      // batch row = mt*16 + p*4 + r  ->  q = mt*4+p, rowInQ = r
      size_t base = (size_t)t * 16384 + (size_t)((mt * 4 + p) * 2048 + gcol * 4 + g);
      if constexpr (XPF32) {
        float* xpf = (float*)xp_out + (size_t)dir * ((size_t)T * 16384);
#pragma unroll
        for (int r = 0; r < 4; ++r) xpf[base + r * 512] = v[r];
      } else {
        unsigned short* xpb = (unsigned short*)xp_out + (size_t)dir * ((size_t)T * 16384);
#pragma unroll
        for (int r = 0; r < 4; ++r) xpb[base + r * 512] = f2bf(v[r]);
      }
    }
  }
}

// ---------------------------------------------------------------------------
// lstm_scan: 16 persistent WGs (blockIdx = dir*8 + octant q), 8 waves each.
// Wave wid owns 16 h-cols (all 4 gates) for 4 batch rows (consecutive-dup).
// Wh in regs; h double-buffered in LDS (4 x 288B, conflict-free); gx unpacked
// straight into persistent MFMA C-quads (elems 1-3 stay 0). 1 barrier/step.
// ---------------------------------------------------------------------------
DEVINL void setc(f32x4& c0, f32x4& c1, f32x4& c2, f32x4& c3, float4 v) {
  c0[0] = v.x; c1[0] = v.y; c2[0] = v.z; c3[0] = v.w;
}
DEVINL void setc(f32x4& c0, f32x4& c1, f32x4& c2, f32x4& c3, uint2 u) {
  c0[0] = __uint_as_float(u.x << 16);
  c1[0] = __uint_as_float(u.x & 0xFFFF0000u);
  c2[0] = __uint_as_float(u.y << 16);
  c3[0] = __uint_as_float(u.y & 0xFFFF0000u);
}

template <int LAYER, bool XPF32>
__global__ __launch_bounds__(512) void lstm_scan(const void* xp, const unsigned short* swh,
                                                 unsigned short* out0, float* dout) {
  using gxT = typename std::conditional<XPF32, float4, uint2>::type;
  int dir = blockIdx.x >> 3;
  int q = blockIdx.x & 7;
  int wid = threadIdx.x >> 6, lane = threadIdx.x & 63;
  int c15 = lane & 15, p = lane >> 4;
  int col = wid * 16 + c15;

  __shared__ __align__(16) unsigned char hA[1280];  // 4 rows x 288B (128 bf16 + pad)
  __shared__ __align__(16) unsigned char hB[1280];

  // Wh fragments (pre-scaled, pre-fragged): 16 contiguous b128 loads
  const unsigned short* whbase = swh + (size_t)LAYER * 131072 + (size_t)dir * 65536;
  short8 whf[4][4];
#pragma unroll
  for (int g = 0; g < 4; ++g)
#pragma unroll
    for (int ks = 0; ks < 4; ++ks)
      whf[g][ks] = *(const short8*)(whbase + g * 16384 + ks * 4096 + wid * 512 + lane * 8);

  if (threadIdx.x < 288) {
    ((unsigned int*)hA)[threadIdx.x] = 0u;
    ((unsigned int*)hB)[threadIdx.x] = 0u;
  }

  // A-frag read offsets: A row m = lane&15 holds real row m>>2 (consecutive dup)
  int aoff[4];
#pragma unroll
  for (int ks = 0; ks < 4; ++ks)
    aoff[ks] = ((lane & 15) >> 2) * 288 + ((lane >> 4) << 4) + ks * 64;
  // h write offset: row p, col
  int woff = p * 288 + col * 2;

  // gx: one gxT per thread per step (uniform base, constant lane index)
  const gxT* gxp = (const gxT*)xp + (size_t)dir * ((size_t)T * 4096);
  int og = q * 512 + p * 128 + col;

  int b = q * 4 + p;                                   // global batch row
  float cs = 0.f;

  int t0 = dir ? (T - 1) : 0;
  int ts = dir ? -1 : 1;

  gxp += (size_t)t0 * 4096;
  // uniform store bases + constant 32-bit lane indices (saddr-form stores)
  unsigned short* outp_u = out0 + (size_t)t0 * 8192;
  float* dp_u = dout + (size_t)t0 * 256;
  unsigned int oidx = (unsigned int)(b * 256 + dir * 128 + col);
  unsigned int didx = (unsigned int)((size_t)b * T * 256 + dir * 128 + col);
  const ptrdiff_t GXS = (ptrdiff_t)ts * 4096;
  const ptrdiff_t OUS = (ptrdiff_t)ts * 8192;
  const ptrdiff_t DPS = (ptrdiff_t)ts * 256;

  // persistent MFMA C-quads: elem 0 = per-step gx, elems 1-3 stay 0 forever
  f32x4 cq0 = {0.f, 0.f, 0.f, 0.f};
  f32x4 cq1 = {0.f, 0.f, 0.f, 0.f};
  f32x4 cq2 = {0.f, 0.f, 0.f, 0.f};
  f32x4 cq3 = {0.f, 0.f, 0.f, 0.f};

  gxT ga = gxp[og];
  gxT gb;
  __syncthreads();

#define STEP(RD, WR, GC, GN)                                                       \
  {                                                                                \
    gxp += GXS;                                                                    \
    GN = gxp[og];            /* next-step gx: issue first, independent */          \
    short8 af0 = *(const short8*)((const char*)(RD) + aoff[0]);                    \
    short8 af1 = *(const short8*)((const char*)(RD) + aoff[1]);                    \
    short8 af2 = *(const short8*)((const char*)(RD) + aoff[2]);                    \
    short8 af3 = *(const short8*)((const char*)(RD) + aoff[3]);                    \
    setc(cq0, cq1, cq2, cq3, GC);  /* unpack current gx into C elem0 */            \
    /* ks0 warm-up: 4 MFMAs need only af0; hides af1-af3 ds_read latency */        \
    f32x4 acc0 = __builtin_amdgcn_mfma_f32_16x16x32_bf16(af0, whf[0][0], cq0, 0,0,0); \
    f32x4 acc1 = __builtin_amdgcn_mfma_f32_16x16x32_bf16(af0, whf[1][0], cq1, 0,0,0); \
    f32x4 acc2 = __builtin_amdgcn_mfma_f32_16x16x32_bf16(af0, whf[2][0], cq2, 0,0,0); \
    f32x4 acc3 = __builtin_amdgcn_mfma_f32_16x16x32_bf16(af0, whf[3][0], cq3, 0,0,0); \
    /* gate-major chains; each gate's exp2 right after its chain so the */         \
    /* trans issue under the following gates' MFMAs */                             \
    acc0 = __builtin_amdgcn_mfma_f32_16x16x32_bf16(af1, whf[0][1], acc0, 0, 0, 0); \
    acc0 = __builtin_amdgcn_mfma_f32_16x16x32_bf16(af2, whf[0][2], acc0, 0, 0, 0); \
    acc0 = __builtin_amdgcn_mfma_f32_16x16x32_bf16(af3, whf[0][3], acc0, 0, 0, 0); \
    float ei = __builtin_amdgcn_exp2f(acc0[0]);                                    \
    acc1 = __builtin_amdgcn_mfma_f32_16x16x32_bf16(af1, whf[1][1], acc1, 0, 0, 0); \
    acc1 = __builtin_amdgcn_mfma_f32_16x16x32_bf16(af2, whf[1][2], acc1, 0, 0, 0); \
    acc1 = __builtin_amdgcn_mfma_f32_16x16x32_bf16(af3, whf[1][3], acc1, 0, 0, 0); \
    float ef = __builtin_amdgcn_exp2f(acc1[0]);                                    \
    acc2 = __builtin_amdgcn_mfma_f32_16x16x32_bf16(af1, whf[2][1], acc2, 0, 0, 0); \
    acc2 = __builtin_amdgcn_mfma_f32_16x16x32_bf16(af2, whf[2][2], acc2, 0, 0, 0); \
    acc2 = __builtin_amdgcn_mfma_f32_16x16x32_bf16(af3, whf[2][3], acc2, 0, 0, 0); \
    float eg = __builtin_amdgcn_exp2f(acc2[0]);                                    \
    acc3 = __builtin_amdgcn_mfma_f32_16x16x32_bf16(af1, whf[3][1], acc3, 0, 0, 0); \
    acc3 = __builtin_amdgcn_mfma_f32_16x16x32_bf16(af2, whf[3][2], acc3, 0, 0, 0); \
    acc3 = __builtin_amdgcn_mfma_f32_16x16x32_bf16(af3, whf[3][3], acc3, 0, 0, 0); \
    float eo = __builtin_amdgcn_exp2f(acc3[0]);                                    \
    /* partial combine for i,f,g issued under gate-3 MFMAs via deps */             \
    float ai = 1.0f + ei, av = 1.0f + ef, ag = 1.0f + eg, sg = 1.0f - eg;          \
    float pp = ai * ag;                                                            \
    float num = __builtin_fmaf(cs, pp, sg * av);                                   \
    float rd = __builtin_amdgcn_rcpf(av * pp);                                     \
    float cn = num * rd;                                                           \
    cs = cn;                                                                       \
    float ec = __builtin_amdgcn_exp2f(M2L2E * cn);                                 \
    float ao = 1.0f + eo, ac = 1.0f + ec, sc = 1.0f - ec;                          \
    float rd2 = __builtin_amdgcn_rcpf(ao * ac);                                    \
    float hv = sc * rd2;                                                           \
    unsigned int pk;                                                               \
    asm("v_cvt_pk_bf16_f32 %0, %1, %2" : "=v"(pk) : "v"(hv), "v"(hv));             \
    unsigned short hb = (unsigned short)pk;                                        \
    *(unsigned short*)((char*)(WR) + woff) = hb;                                   \
    if (LAYER == 0) {                                                              \
      outp_u[oidx] = hb;                                                           \
      outp_u += OUS;                                                               \
    } else {                                                                       \
      dp_u[didx] = hv;                                                             \
      dp_u += DPS;                                                                 \
    }                                                                              \
    asm volatile("s_waitcnt lgkmcnt(0)" ::: "memory");                             \
    __builtin_amdgcn_s_barrier();                                                  \
    asm volatile("" ::: "memory");                                                 \
  }

  for (int s = 0; s < T; s += 4) {
    STEP(hA, hB, ga, gb);
    STEP(hB, hA, gb, ga);
    STEP(hA, hB, ga, gb);
    STEP(hB, hA, gb, ga);
  }
#undef STEP

  if constexpr (LAYER == 1) {
    dout[XOUT + (size_t)b * 256 + dir * 128 + col] = cs;
  }
}

// ---------------------------------------------------------------------------
extern "C" void kernel_launch(void* const* d_in, const int* in_sizes, int n_in,
                              void* d_out, int out_size, void* d_ws, size_t ws_size,
                              hipStream_t stream) {
  const float* x    = (const float*)d_in[0];
  const float* wxf0 = (const float*)d_in[1];
  const float* whf0 = (const float*)d_in[2];
  const float* wxb0 = (const float*)d_in[3];
  const float* whb0 = (const float*)d_in[4];
  const float* wxf1 = (const float*)d_in[5];
  const float* whf1 = (const float*)d_in[6];
  const float* wxb1 = (const float*)d_in[7];
  const float* whb1 = (const float*)d_in[8];
  const float* bf0  = (const float*)d_in[9];
  const float* bb0  = (const float*)d_in[10];
  const float* bf1  = (const float*)d_in[11];
  const float* bb1  = (const float*)d_in[12];
  float* dout = (float*)d_out;

  // ws: [xp][out0 bf16][sw0][sw1][swh]
  const size_t needF32 = 268435456u + 33554432u + 262144u + 524288u + 524288u;
  bool xpf32 = ws_size >= needF32;
  size_t xpBytes = xpf32 ? 268435456u : 134217728u;
  unsigned char* ws = (unsigned char*)d_ws;
  void* xp = (void*)ws;
  unsigned short* out0 = (unsigned short*)(ws + xpBytes);
  unsigned short* sw0  = (unsigned short*)(ws + xpBytes + 33554432u);
  unsigned short* sw1  = sw0 + 2 * 65536;
  unsigned short* swh  = sw1 + 2 * 131072;

  prep_wx<<<1536, 256, 0, stream>>>(wxf0, wxb0, wxf1, wxb1, sw0, sw1);
  prep_wh<<<1024, 256, 0, stream>>>(whf0, whb0, whf1, whb1, swh);

  if (xpf32) {
    input_proj<0, true><<<dim3(2048, 2), 256, 0, stream>>>(x, nullptr, sw0, bf0, bb0, xp);
    lstm_scan<0, true><<<16, 512, 0, stream>>>(xp, swh, out0, dout);
    input_proj<1, true><<<dim3(2048, 2), 256, 0, stream>>>(nullptr, out0, sw1, bf1, bb1, xp);
    lstm_scan<1, true><<<16, 512, 0, stream>>>(xp, swh, out0, dout);
  } else {
    input_proj<0, false><<<dim3(2048, 2), 256, 0, stream>>>(x, nullptr, sw0, bf0, bb0, xp);
    lstm_scan<0, false><<<16, 512, 0, stream>>>(xp, swh, out0, dout);
    input_proj<1, false><<<dim3(2048, 2), 256, 0, stream>>>(nullptr, out0, sw1, bf1, bb1, xp);
    lstm_scan<1, false><<<16, 512, 0, stream>>>(xp, swh, out0, dout);
  }
}

// Round 9
// 1929.299 us; speedup vs baseline: 1.1859x; 1.1859x over previous
//
#include <hip/hip_runtime.h>
#include <hip/hip_bf16.h>
#include <stdint.h>
#include <type_traits>

// Bidirectional 2-layer LSTM, B=32, T=2048, F=H=128, G=4H=512.
// prep (Wx,Wh -> scaled bf16 frags) -> proj L0 -> scan L0 (16 WGs: dir x 8
// batch-octants of 4 rows) -> proj L1 -> scan L1. Gate pre-activations are
// pre-scaled by -log2e (i,f,o) / -2log2e (g) so sigmoid = rcp(1+exp2(y)).
// 7-trans common-denominator activation; 1 state elem per lane. Rows are
// duplicated CONSECUTIVELY (A row m = real row m>>2) so every acc reg of
// lane-group p equals real row p -> no select tree. Gate-major MFMA order.
// R9 = R7 (known-good) + s_setprio(1) around the MFMA cluster (T5): the two
// waves per SIMD drift into anti-phase; priority keeps the matrix pipe fed
// while the other wave runs its activation VALU.

#define DEVINL __device__ __forceinline__

typedef __attribute__((ext_vector_type(8))) short short8;
typedef __attribute__((ext_vector_type(4))) float f32x4;

static constexpr int T = 2048;
static constexpr size_t XOUT = (size_t)32 * T * 256;
static constexpr float L2E = 1.4426950408889634f;
static constexpr float M2L2E = -2.8853900817779268f;

DEVINL unsigned short f2bf(float f) {
  unsigned int u = __float_as_uint(f);
  u += 0x7FFFu + ((u >> 16) & 1u);  // RNE
  return (unsigned short)(u >> 16);
}
DEVINL float gate_scale(int g) { return (g == 2) ? M2L2E : -L2E; }

// ---------------------------------------------------------------------------
// prep_wx: Wx (f32 [K][512]) -> scaled bf16 B-frags [dir][ng(32)][ks][lane][e8]
// ---------------------------------------------------------------------------
__global__ __launch_bounds__(256) void prep_wx(const float* wxf0, const float* wxb0,
                                               const float* wxf1, const float* wxb1,
                                               unsigned short* sw0, unsigned short* sw1) {
  int idx = blockIdx.x * 256 + threadIdx.x;
  if (idx < 2 * 65536) {                       // layer 0, KS=4
    int d = idx >> 16;
    int local = idx & 65535;
    const float* w = d ? wxb0 : wxf0;
    int e = local & 7, lane = (local >> 3) & 63, ks = (local >> 9) & 3, ng = local >> 11;
    int col = ng * 16 + (lane & 15);
    int k = ks * 32 + ((lane >> 4) << 3) + e;
    sw0[idx] = f2bf(w[k * 512 + col] * gate_scale(ng >> 3));
  } else {                                     // layer 1, KS=8
    int j = idx - 2 * 65536;
    if (j < 2 * 131072) {
      int d = j >> 17;
      int local = j & 131071;
      const float* w = d ? wxb1 : wxf1;
      int e = local & 7, lane = (local >> 3) & 63, ks = (local >> 9) & 7, ng = local >> 12;
      int col = ng * 16 + (lane & 15);
      int k = ks * 32 + ((lane >> 4) << 3) + e;
      sw1[j] = f2bf(w[k * 512 + col] * gate_scale(ng >> 3));
    }
  }
}

// ---------------------------------------------------------------------------
// prep_wh: Wh (f32 [128][512]) -> scaled bf16 frags, contiguous per wave:
// idx bits: e(0-2) lane(3-8) wid(9-11) ks(12-13) g(14-15) dir(16) layer(17)
// ---------------------------------------------------------------------------
__global__ __launch_bounds__(256) void prep_wh(const float* whf0, const float* whb0,
                                               const float* whf1, const float* whb1,
                                               unsigned short* swh) {
  int idx = blockIdx.x * 256 + threadIdx.x;
  if (idx >= 262144) return;
  int e = idx & 7, lane = (idx >> 3) & 63, wid = (idx >> 9) & 7;
  int ks = (idx >> 12) & 3, g = (idx >> 14) & 3, dir = (idx >> 16) & 1, layer = (idx >> 17) & 1;
  const float* w = layer ? (dir ? whb1 : whf1) : (dir ? whb0 : whf0);
  int col = g * 128 + wid * 16 + (lane & 15);
  int k = ks * 32 + ((lane >> 4) << 3) + e;
  swh[idx] = f2bf(w[k * 512 + col] * gate_scale(g));
}

// ---------------------------------------------------------------------------
// input_proj: xp[dir][t][q(8)][row(4)][col(128)][g(4)] = A(t)@Wx_scaled + b.
// Scan thread (q, row=p, col) then loads ONE float4/uint2 (4 gates).
// ---------------------------------------------------------------------------
template <int LAYER, bool XPF32>
__global__ __launch_bounds__(256) void input_proj(const float* x, const unsigned short* a_bf,
                                                  const unsigned short* wsw,
                                                  const float* bias_f, const float* bias_b,
                                                  void* xp_out) {
  constexpr int KS = (LAYER == 0) ? 4 : 8;
  int t = blockIdx.x, dir = blockIdx.y;
  int wid = threadIdx.x >> 6, lane = threadIdx.x & 63;   // wid = 0..3
  int p = lane >> 4, c15 = lane & 15;
  const unsigned short* wbase = wsw + (size_t)dir * (32 * KS * 64 * 8);
  const float* bias = dir ? bias_b : bias_f;

  short8 afrag[2][KS];
#pragma unroll
  for (int mt = 0; mt < 2; ++mt) {
#pragma unroll
    for (int ks = 0; ks < KS; ++ks) {
      int m = c15 + mt * 16;
      int kk = ks * 32 + (p << 3);
      if constexpr (LAYER == 0) {
        const float* ap = x + (size_t)m * (T * 128) + (size_t)t * 128 + kk;
        float4 lov = *(const float4*)ap;
        float4 hiv = *(const float4*)(ap + 4);
        short8 s;
        s[0] = (short)f2bf(lov.x); s[1] = (short)f2bf(lov.y);
        s[2] = (short)f2bf(lov.z); s[3] = (short)f2bf(lov.w);
        s[4] = (short)f2bf(hiv.x); s[5] = (short)f2bf(hiv.y);
        s[6] = (short)f2bf(hiv.z); s[7] = (short)f2bf(hiv.w);
        afrag[mt][ks] = s;
      } else {
        afrag[mt][ks] = *(const short8*)(a_bf + ((size_t)t * 32 + m) * 256 + kk);
      }
    }
  }

#pragma unroll
  for (int ngi = 0; ngi < 8; ++ngi) {
    int ng = wid * 8 + ngi;
    int g = ng >> 3, wd = ng & 7;
    f32x4 acc0 = {0.f, 0.f, 0.f, 0.f};
    f32x4 acc1 = {0.f, 0.f, 0.f, 0.f};
#pragma unroll
    for (int ks = 0; ks < KS; ++ks) {
      short8 b = *(const short8*)(wbase + ((size_t)(ng * KS + ks) * 64 + lane) * 8);
      acc0 = __builtin_amdgcn_mfma_f32_16x16x32_bf16(afrag[0][ks], b, acc0, 0, 0, 0);
      acc1 = __builtin_amdgcn_mfma_f32_16x16x32_bf16(afrag[1][ks], b, acc1, 0, 0, 0);
    }
    float bs = bias[ng * 16 + c15] * gate_scale(g);
    int gcol = wd * 16 + c15;
#pragma unroll
    for (int mt = 0; mt < 2; ++mt) {
      f32x4 v = (mt == 0) ? acc0 : acc1;
      v[0] += bs; v[1] += bs; v[2] += bs; v[3] += bs;
      // batch row = mt*16 + p*4 + r  ->  q = mt*4+p, rowInQ = r
      size_t base = (size_t)t * 16384 + (size_t)((mt * 4 + p) * 2048 + gcol * 4 + g);
      if constexpr (XPF32) {
        float* xpf = (float*)xp_out + (size_t)dir * ((size_t)T * 16384);
#pragma unroll
        for (int r = 0; r < 4; ++r) xpf[base + r * 512] = v[r];
      } else {
        unsigned short* xpb = (unsigned short*)xp_out + (size_t)dir * ((size_t)T * 16384);
#pragma unroll
        for (int r = 0; r < 4; ++r) xpb[base + r * 512] = f2bf(v[r]);
      }
    }
  }
}

// ---------------------------------------------------------------------------
// lstm_scan: 16 persistent WGs (blockIdx = dir*8 + octant q), 8 waves each.
// Wave wid owns 16 h-cols (all 4 gates) for 4 batch rows (consecutive-dup in
// the M-tile: A row m = real row m>>2, so lane-group p's acc[0..3] all equal
// real row p). Wh in regs; h double-buffered in LDS (4 x 288B, conflict-free);
// gx = one float4/uint2 per thread, prefetched 1 step ahead. 1 barrier/step.
// ---------------------------------------------------------------------------
DEVINL f32x4 gx2v(float4 v) { f32x4 r; r[0]=v.x; r[1]=v.y; r[2]=v.z; r[3]=v.w; return r; }
DEVINL f32x4 gx2v(uint2 u) {
  f32x4 r;
  r[0] = __uint_as_float(u.x << 16);
  r[1] = __uint_as_float(u.x & 0xFFFF0000u);
  r[2] = __uint_as_float(u.y << 16);
  r[3] = __uint_as_float(u.y & 0xFFFF0000u);
  return r;
}

template <int LAYER, bool XPF32>
__global__ __launch_bounds__(512) void lstm_scan(const void* xp, const unsigned short* swh,
                                                 unsigned short* out0, float* dout) {
  using gxT = typename std::conditional<XPF32, float4, uint2>::type;
  int dir = blockIdx.x >> 3;
  int q = blockIdx.x & 7;
  int wid = threadIdx.x >> 6, lane = threadIdx.x & 63;
  int c15 = lane & 15, p = lane >> 4;
  int col = wid * 16 + c15;

  __shared__ __align__(16) unsigned char hA[1280];  // 4 rows x 288B (128 bf16 + pad)
  __shared__ __align__(16) unsigned char hB[1280];

  // Wh fragments (pre-scaled, pre-fragged): 16 contiguous b128 loads
  const unsigned short* whbase = swh + (size_t)LAYER * 131072 + (size_t)dir * 65536;
  short8 whf[4][4];
#pragma unroll
  for (int g = 0; g < 4; ++g)
#pragma unroll
    for (int ks = 0; ks < 4; ++ks)
      whf[g][ks] = *(const short8*)(whbase + g * 16384 + ks * 4096 + wid * 512 + lane * 8);

  if (threadIdx.x < 288) {
    ((unsigned int*)hA)[threadIdx.x] = 0u;
    ((unsigned int*)hB)[threadIdx.x] = 0u;
  }

  // A-frag read offsets: A row m = lane&15 holds real row m>>2 (consecutive dup)
  int aoff[4];
#pragma unroll
  for (int ks = 0; ks < 4; ++ks)
    aoff[ks] = ((lane & 15) >> 2) * 288 + ((lane >> 4) << 4) + ks * 64;
  // h write offset: row p, col
  int woff = p * 288 + col * 2;

  // gx: one gxT per thread per step (uniform base, constant lane index)
  const gxT* gxp = (const gxT*)xp + (size_t)dir * ((size_t)T * 4096);
  int og = q * 512 + p * 128 + col;

  int b = q * 4 + p;                                   // global batch row
  float cs = 0.f;

  int t0 = dir ? (T - 1) : 0;
  int ts = dir ? -1 : 1;

  gxp += (size_t)t0 * 4096;
  // uniform store bases + constant 32-bit lane indices (saddr-form stores)
  unsigned short* outp_u = out0 + (size_t)t0 * 8192;
  float* dp_u = dout + (size_t)t0 * 256;
  unsigned int oidx = (unsigned int)(b * 256 + dir * 128 + col);
  unsigned int didx = (unsigned int)((size_t)b * T * 256 + dir * 128 + col);
  const ptrdiff_t GXS = (ptrdiff_t)ts * 4096;
  const ptrdiff_t OUS = (ptrdiff_t)ts * 8192;
  const ptrdiff_t DPS = (ptrdiff_t)ts * 256;

  gxT ga = gxp[og];
  gxT gb;
  __syncthreads();

#define STEP(RD, WR, GC, GN)                                                       \
  {                                                                                \
    short8 af0 = *(const short8*)((const char*)(RD) + aoff[0]);                    \
    short8 af1 = *(const short8*)((const char*)(RD) + aoff[1]);                    \
    short8 af2 = *(const short8*)((const char*)(RD) + aoff[2]);                    \
    short8 af3 = *(const short8*)((const char*)(RD) + aoff[3]);                    \
    const f32x4 zz = {0.f, 0.f, 0.f, 0.f};                                         \
    f32x4 gv = gx2v(GC);                                                           \
    __builtin_amdgcn_s_setprio(1);                                                 \
    /* gate 0 (i) */                                                               \
    f32x4 acc0 = __builtin_amdgcn_mfma_f32_16x16x32_bf16(af0, whf[0][0], zz, 0,0,0); \
    acc0 = __builtin_amdgcn_mfma_f32_16x16x32_bf16(af1, whf[0][1], acc0, 0, 0, 0); \
    acc0 = __builtin_amdgcn_mfma_f32_16x16x32_bf16(af2, whf[0][2], acc0, 0, 0, 0); \
    acc0 = __builtin_amdgcn_mfma_f32_16x16x32_bf16(af3, whf[0][3], acc0, 0, 0, 0); \
    float ei = __builtin_amdgcn_exp2f(acc0[0] + gv[0]);                            \
    /* gate 1 (f) */                                                               \
    f32x4 acc1 = __builtin_amdgcn_mfma_f32_16x16x32_bf16(af0, whf[1][0], zz, 0,0,0); \
    acc1 = __builtin_amdgcn_mfma_f32_16x16x32_bf16(af1, whf[1][1], acc1, 0, 0, 0); \
    acc1 = __builtin_amdgcn_mfma_f32_16x16x32_bf16(af2, whf[1][2], acc1, 0, 0, 0); \
    acc1 = __builtin_amdgcn_mfma_f32_16x16x32_bf16(af3, whf[1][3], acc1, 0, 0, 0); \
    float ef = __builtin_amdgcn_exp2f(acc1[0] + gv[1]);                            \
    gxp += GXS;                                                                    \
    GN = gxp[og];                                                                  \
    /* gate 2 (g) */                                                               \
    f32x4 acc2 = __builtin_amdgcn_mfma_f32_16x16x32_bf16(af0, whf[2][0], zz, 0,0,0); \
    acc2 = __builtin_amdgcn_mfma_f32_16x16x32_bf16(af1, whf[2][1], acc2, 0, 0, 0); \
    acc2 = __builtin_amdgcn_mfma_f32_16x16x32_bf16(af2, whf[2][2], acc2, 0, 0, 0); \
    acc2 = __builtin_amdgcn_mfma_f32_16x16x32_bf16(af3, whf[2][3], acc2, 0, 0, 0); \
    float eg = __builtin_amdgcn_exp2f(acc2[0] + gv[2]);                            \
    /* gate 3 (o) */                                                               \
    f32x4 acc3 = __builtin_amdgcn_mfma_f32_16x16x32_bf16(af0, whf[3][0], zz, 0,0,0); \
    acc3 = __builtin_amdgcn_mfma_f32_16x16x32_bf16(af1, whf[3][1], acc3, 0, 0, 0); \
    acc3 = __builtin_amdgcn_mfma_f32_16x16x32_bf16(af2, whf[3][2], acc3, 0, 0, 0); \
    acc3 = __builtin_amdgcn_mfma_f32_16x16x32_bf16(af3, whf[3][3], acc3, 0, 0, 0); \
    __builtin_amdgcn_s_setprio(0);                                                 \
    float eo = __builtin_amdgcn_exp2f(acc3[0] + gv[3]);                            \
    /* combine: 7-trans common-denominator activation */                           \
    float ai = 1.0f + ei, av = 1.0f + ef, ag = 1.0f + eg, sg = 1.0f - eg;          \
    float pp = ai * ag;                                                            \
    float num = __builtin_fmaf(cs, pp, sg * av);                                   \
    float rd = __builtin_amdgcn_rcpf(av * pp);                                     \
    float cn = num * rd;                                                           \
    cs = cn;                                                                       \
    float ec = __builtin_amdgcn_exp2f(M2L2E * cn);                                 \
    float ao = 1.0f + eo, ac = 1.0f + ec, sc = 1.0f - ec;                          \
    float rd2 = __builtin_amdgcn_rcpf(ao * ac);                                    \
    float hv = sc * rd2;                                                           \
    unsigned int pk;                                                               \
    asm("v_cvt_pk_bf16_f32 %0, %1, %2" : "=v"(pk) : "v"(hv), "v"(hv));             \
    unsigned short hb = (unsigned short)pk;                                        \
    *(unsigned short*)((char*)(WR) + woff) = hb;                                   \
    if (LAYER == 0) {                                                              \
      outp_u[oidx] = hb;                                                           \
      outp_u += OUS;                                                               \
    } else {                                                                       \
      dp_u[didx] = hv;                                                             \
      dp_u += DPS;                                                                 \
    }                                                                              \
    asm volatile("s_waitcnt lgkmcnt(0)" ::: "memory");                             \
    __builtin_amdgcn_s_barrier();                                                  \
    asm volatile("" ::: "memory");                                                 \
  }

  for (int s = 0; s < T; s += 4) {
    STEP(hA, hB, ga, gb);
    STEP(hB, hA, gb, ga);
    STEP(hA, hB, ga, gb);
    STEP(hB, hA, gb, ga);
  }
#undef STEP

  if constexpr (LAYER == 1) {
    dout[XOUT + (size_t)b * 256 + dir * 128 + col] = cs;
  }
}

// ---------------------------------------------------------------------------
extern "C" void kernel_launch(void* const* d_in, const int* in_sizes, int n_in,
                              void* d_out, int out_size, void* d_ws, size_t ws_size,
                              hipStream_t stream) {
  const float* x    = (const float*)d_in[0];
  const float* wxf0 = (const float*)d_in[1];
  const float* whf0 = (const float*)d_in[2];
  const float* wxb0 = (const float*)d_in[3];
  const float* whb0 = (const float*)d_in[4];
  const float* wxf1 = (const float*)d_in[5];
  const float* whf1 = (const float*)d_in[6];
  const float* wxb1 = (const float*)d_in[7];
  const float* whb1 = (const float*)d_in[8];
  const float* bf0  = (const float*)d_in[9];
  const float* bb0  = (const float*)d_in[10];
  const float* bf1  = (const float*)d_in[11];
  const float* bb1  = (const float*)d_in[12];
  float* dout = (float*)d_out;

  // ws: [xp][out0 bf16][sw0][sw1][swh]
  const size_t needF32 = 268435456u + 33554432u + 262144u + 524288u + 524288u;
  bool xpf32 = ws_size >= needF32;
  size_t xpBytes = xpf32 ? 268435456u : 134217728u;
  unsigned char* ws = (unsigned char*)d_ws;
  void* xp = (void*)ws;
  unsigned short* out0 = (unsigned short*)(ws + xpBytes);
  unsigned short* sw0  = (unsigned short*)(ws + xpBytes + 33554432u);
  unsigned short* sw1  = sw0 + 2 * 65536;
  unsigned short* swh  = sw1 + 2 * 131072;

  prep_wx<<<1536, 256, 0, stream>>>(wxf0, wxb0, wxf1, wxb1, sw0, sw1);
  prep_wh<<<1024, 256, 0, stream>>>(whf0, whb0, whf1, whb1, swh);

  if (xpf32) {
    input_proj<0, true><<<dim3(2048, 2), 256, 0, stream>>>(x, nullptr, sw0, bf0, bb0, xp);
    lstm_scan<0, true><<<16, 512, 0, stream>>>(xp, swh, out0, dout);
    input_proj<1, true><<<dim3(2048, 2), 256, 0, stream>>>(nullptr, out0, sw1, bf1, bb1, xp);
    lstm_scan<1, true><<<16, 512, 0, stream>>>(xp, swh, out0, dout);
  } else {
    input_proj<0, false><<<dim3(2048, 2), 256, 0, stream>>>(x, nullptr, sw0, bf0, bb0, xp);
    lstm_scan<0, false><<<16, 512, 0, stream>>>(xp, swh, out0, dout);
    input_proj<1, false><<<dim3(2048, 2), 256, 0, stream>>>(nullptr, out0, sw1, bf1, bb1, xp);
    lstm_scan<1, false><<<16, 512, 0, stream>>>(xp, swh, out0, dout);
  }
}

// Round 10
// 1783.541 us; speedup vs baseline: 1.2828x; 1.0817x over previous
//
#include <hip/hip_runtime.h>
#include <hip/hip_bf16.h>
#include <stdint.h>
#include <type_traits>

// Bidirectional 2-layer LSTM, B=32, T=2048, F=H=128, G=4H=512.
// prep (Wx,Wh -> scaled bf16 frags) -> proj L0 -> scan L0 (16 WGs: dir x 8
// batch-octants of 4 rows) -> proj L1 -> scan L1. Gate pre-activations are
// pre-scaled by -log2e (i,f,o) / -2log2e (g) so sigmoid = rcp(1+exp2(y)).
// 7-trans common-denominator activation; 1 state elem per lane. Rows are
// duplicated CONSECUTIVELY (A row m = real row m>>2) so every acc reg of
// lane-group p equals real row p -> no select tree. Gate-major MFMA order
// lets each gate's exp2 issue under the remaining MFMAs.
// R10 = exact R7 revert (measured best: 811 us/scan, per-CU MFMA+VALU=98.5%).
// Ledger: R8 (gx->MFMA C-operand hand-schedule) -31%; R9 (setprio T5) -8%.
// Both overlap attempts regressed -> compiler's schedule of this source is
// the best found; do not re-perturb.

#define DEVINL __device__ __forceinline__

typedef __attribute__((ext_vector_type(8))) short short8;
typedef __attribute__((ext_vector_type(4))) float f32x4;

static constexpr int T = 2048;
static constexpr size_t XOUT = (size_t)32 * T * 256;
static constexpr float L2E = 1.4426950408889634f;
static constexpr float M2L2E = -2.8853900817779268f;

DEVINL unsigned short f2bf(float f) {
  unsigned int u = __float_as_uint(f);
  u += 0x7FFFu + ((u >> 16) & 1u);  // RNE
  return (unsigned short)(u >> 16);
}
DEVINL float gate_scale(int g) { return (g == 2) ? M2L2E : -L2E; }

// ---------------------------------------------------------------------------
// prep_wx: Wx (f32 [K][512]) -> scaled bf16 B-frags [dir][ng(32)][ks][lane][e8]
// ---------------------------------------------------------------------------
__global__ __launch_bounds__(256) void prep_wx(const float* wxf0, const float* wxb0,
                                               const float* wxf1, const float* wxb1,
                                               unsigned short* sw0, unsigned short* sw1) {
  int idx = blockIdx.x * 256 + threadIdx.x;
  if (idx < 2 * 65536) {                       // layer 0, KS=4
    int d = idx >> 16;
    int local = idx & 65535;
    const float* w = d ? wxb0 : wxf0;
    int e = local & 7, lane = (local >> 3) & 63, ks = (local >> 9) & 3, ng = local >> 11;
    int col = ng * 16 + (lane & 15);
    int k = ks * 32 + ((lane >> 4) << 3) + e;
    sw0[idx] = f2bf(w[k * 512 + col] * gate_scale(ng >> 3));
  } else {                                     // layer 1, KS=8
    int j = idx - 2 * 65536;
    if (j < 2 * 131072) {
      int d = j >> 17;
      int local = j & 131071;
      const float* w = d ? wxb1 : wxf1;
      int e = local & 7, lane = (local >> 3) & 63, ks = (local >> 9) & 7, ng = local >> 12;
      int col = ng * 16 + (lane & 15);
      int k = ks * 32 + ((lane >> 4) << 3) + e;
      sw1[j] = f2bf(w[k * 512 + col] * gate_scale(ng >> 3));
    }
  }
}

// ---------------------------------------------------------------------------
// prep_wh: Wh (f32 [128][512]) -> scaled bf16 frags, contiguous per wave:
// idx bits: e(0-2) lane(3-8) wid(9-11) ks(12-13) g(14-15) dir(16) layer(17)
// ---------------------------------------------------------------------------
__global__ __launch_bounds__(256) void prep_wh(const float* whf0, const float* whb0,
                                               const float* whf1, const float* whb1,
                                               unsigned short* swh) {
  int idx = blockIdx.x * 256 + threadIdx.x;
  if (idx >= 262144) return;
  int e = idx & 7, lane = (idx >> 3) & 63, wid = (idx >> 9) & 7;
  int ks = (idx >> 12) & 3, g = (idx >> 14) & 3, dir = (idx >> 16) & 1, layer = (idx >> 17) & 1;
  const float* w = layer ? (dir ? whb1 : whf1) : (dir ? whb0 : whf0);
  int col = g * 128 + wid * 16 + (lane & 15);
  int k = ks * 32 + ((lane >> 4) << 3) + e;
  swh[idx] = f2bf(w[k * 512 + col] * gate_scale(g));
}

// ---------------------------------------------------------------------------
// input_proj: xp[dir][t][q(8)][row(4)][col(128)][g(4)] = A(t)@Wx_scaled + b.
// Scan thread (q, row=p, col) then loads ONE float4/uint2 (4 gates).
// ---------------------------------------------------------------------------
template <int LAYER, bool XPF32>
__global__ __launch_bounds__(256) void input_proj(const float* x, const unsigned short* a_bf,
                                                  const unsigned short* wsw,
                                                  const float* bias_f, const float* bias_b,
                                                  void* xp_out) {
  constexpr int KS = (LAYER == 0) ? 4 : 8;
  int t = blockIdx.x, dir = blockIdx.y;
  int wid = threadIdx.x >> 6, lane = threadIdx.x & 63;   // wid = 0..3
  int p = lane >> 4, c15 = lane & 15;
  const unsigned short* wbase = wsw + (size_t)dir * (32 * KS * 64 * 8);
  const float* bias = dir ? bias_b : bias_f;

  short8 afrag[2][KS];
#pragma unroll
  for (int mt = 0; mt < 2; ++mt) {
#pragma unroll
    for (int ks = 0; ks < KS; ++ks) {
      int m = c15 + mt * 16;
      int kk = ks * 32 + (p << 3);
      if constexpr (LAYER == 0) {
        const float* ap = x + (size_t)m * (T * 128) + (size_t)t * 128 + kk;
        float4 lov = *(const float4*)ap;
        float4 hiv = *(const float4*)(ap + 4);
        short8 s;
        s[0] = (short)f2bf(lov.x); s[1] = (short)f2bf(lov.y);
        s[2] = (short)f2bf(lov.z); s[3] = (short)f2bf(lov.w);
        s[4] = (short)f2bf(hiv.x); s[5] = (short)f2bf(hiv.y);
        s[6] = (short)f2bf(hiv.z); s[7] = (short)f2bf(hiv.w);
        afrag[mt][ks] = s;
      } else {
        afrag[mt][ks] = *(const short8*)(a_bf + ((size_t)t * 32 + m) * 256 + kk);
      }
    }
  }

#pragma unroll
  for (int ngi = 0; ngi < 8; ++ngi) {
    int ng = wid * 8 + ngi;
    int g = ng >> 3, wd = ng & 7;
    f32x4 acc0 = {0.f, 0.f, 0.f, 0.f};
    f32x4 acc1 = {0.f, 0.f, 0.f, 0.f};
#pragma unroll
    for (int ks = 0; ks < KS; ++ks) {
      short8 b = *(const short8*)(wbase + ((size_t)(ng * KS + ks) * 64 + lane) * 8);
      acc0 = __builtin_amdgcn_mfma_f32_16x16x32_bf16(afrag[0][ks], b, acc0, 0, 0, 0);
      acc1 = __builtin_amdgcn_mfma_f32_16x16x32_bf16(afrag[1][ks], b, acc1, 0, 0, 0);
    }
    float bs = bias[ng * 16 + c15] * gate_scale(g);
    int gcol = wd * 16 + c15;
#pragma unroll
    for (int mt = 0; mt < 2; ++mt) {
      f32x4 v = (mt == 0) ? acc0 : acc1;
      v[0] += bs; v[1] += bs; v[2] += bs; v[3] += bs;
      // batch row = mt*16 + p*4 + r  ->  q = mt*4+p, rowInQ = r
      size_t base = (size_t)t * 16384 + (size_t)((mt * 4 + p) * 2048 + gcol * 4 + g);
      if constexpr (XPF32) {
        float* xpf = (float*)xp_out + (size_t)dir * ((size_t)T * 16384);
#pragma unroll
        for (int r = 0; r < 4; ++r) xpf[base + r * 512] = v[r];
      } else {
        unsigned short* xpb = (unsigned short*)xp_out + (size_t)dir * ((size_t)T * 16384);
#pragma unroll
        for (int r = 0; r < 4; ++r) xpb[base + r * 512] = f2bf(v[r]);
      }
    }
  }
}

// ---------------------------------------------------------------------------
// lstm_scan: 16 persistent WGs (blockIdx = dir*8 + octant q), 8 waves each.
// Wave wid owns 16 h-cols (all 4 gates) for 4 batch rows (consecutive-dup in
// the M-tile: A row m = real row m>>2, so lane-group p's acc[0..3] all equal
// real row p). Wh in regs; h double-buffered in LDS (4 x 288B, conflict-free);
// gx = one float4/uint2 per thread, prefetched 1 step ahead. 1 barrier/step.
// ---------------------------------------------------------------------------
DEVINL f32x4 gx2v(float4 v) { f32x4 r; r[0]=v.x; r[1]=v.y; r[2]=v.z; r[3]=v.w; return r; }
DEVINL f32x4 gx2v(uint2 u) {
  f32x4 r;
  r[0] = __uint_as_float(u.x << 16);
  r[1] = __uint_as_float(u.x & 0xFFFF0000u);
  r[2] = __uint_as_float(u.y << 16);
  r[3] = __uint_as_float(u.y & 0xFFFF0000u);
  return r;
}

template <int LAYER, bool XPF32>
__global__ __launch_bounds__(512) void lstm_scan(const void* xp, const unsigned short* swh,
                                                 unsigned short* out0, float* dout) {
  using gxT = typename std::conditional<XPF32, float4, uint2>::type;
  int dir = blockIdx.x >> 3;
  int q = blockIdx.x & 7;
  int wid = threadIdx.x >> 6, lane = threadIdx.x & 63;
  int c15 = lane & 15, p = lane >> 4;
  int col = wid * 16 + c15;

  __shared__ __align__(16) unsigned char hA[1280];  // 4 rows x 288B (128 bf16 + pad)
  __shared__ __align__(16) unsigned char hB[1280];

  // Wh fragments (pre-scaled, pre-fragged): 16 contiguous b128 loads
  const unsigned short* whbase = swh + (size_t)LAYER * 131072 + (size_t)dir * 65536;
  short8 whf[4][4];
#pragma unroll
  for (int g = 0; g < 4; ++g)
#pragma unroll
    for (int ks = 0; ks < 4; ++ks)
      whf[g][ks] = *(const short8*)(whbase + g * 16384 + ks * 4096 + wid * 512 + lane * 8);

  if (threadIdx.x < 288) {
    ((unsigned int*)hA)[threadIdx.x] = 0u;
    ((unsigned int*)hB)[threadIdx.x] = 0u;
  }

  // A-frag read offsets: A row m = lane&15 holds real row m>>2 (consecutive dup)
  int aoff[4];
#pragma unroll
  for (int ks = 0; ks < 4; ++ks)
    aoff[ks] = ((lane & 15) >> 2) * 288 + ((lane >> 4) << 4) + ks * 64;
  // h write offset: row p, col
  int woff = p * 288 + col * 2;

  // gx: one gxT per thread per step (uniform base, constant lane index)
  const gxT* gxp = (const gxT*)xp + (size_t)dir * ((size_t)T * 4096);
  int og = q * 512 + p * 128 + col;

  int b = q * 4 + p;                                   // global batch row
  float cs = 0.f;

  int t0 = dir ? (T - 1) : 0;
  int ts = dir ? -1 : 1;

  gxp += (size_t)t0 * 4096;
  // uniform store bases + constant 32-bit lane indices (saddr-form stores)
  unsigned short* outp_u = out0 + (size_t)t0 * 8192;
  float* dp_u = dout + (size_t)t0 * 256;
  unsigned int oidx = (unsigned int)(b * 256 + dir * 128 + col);
  unsigned int didx = (unsigned int)((size_t)b * T * 256 + dir * 128 + col);
  const ptrdiff_t GXS = (ptrdiff_t)ts * 4096;
  const ptrdiff_t OUS = (ptrdiff_t)ts * 8192;
  const ptrdiff_t DPS = (ptrdiff_t)ts * 256;

  gxT ga = gxp[og];
  gxT gb;
  __syncthreads();

#define STEP(RD, WR, GC, GN)                                                       \
  {                                                                                \
    short8 af0 = *(const short8*)((const char*)(RD) + aoff[0]);                    \
    short8 af1 = *(const short8*)((const char*)(RD) + aoff[1]);                    \
    short8 af2 = *(const short8*)((const char*)(RD) + aoff[2]);                    \
    short8 af3 = *(const short8*)((const char*)(RD) + aoff[3]);                    \
    const f32x4 zz = {0.f, 0.f, 0.f, 0.f};                                         \
    f32x4 gv = gx2v(GC);                                                           \
    /* gate 0 (i) */                                                               \
    f32x4 acc0 = __builtin_amdgcn_mfma_f32_16x16x32_bf16(af0, whf[0][0], zz, 0,0,0); \
    acc0 = __builtin_amdgcn_mfma_f32_16x16x32_bf16(af1, whf[0][1], acc0, 0, 0, 0); \
    acc0 = __builtin_amdgcn_mfma_f32_16x16x32_bf16(af2, whf[0][2], acc0, 0, 0, 0); \
    acc0 = __builtin_amdgcn_mfma_f32_16x16x32_bf16(af3, whf[0][3], acc0, 0, 0, 0); \
    float ei = __builtin_amdgcn_exp2f(acc0[0] + gv[0]);                            \
    /* gate 1 (f) */                                                               \
    f32x4 acc1 = __builtin_amdgcn_mfma_f32_16x16x32_bf16(af0, whf[1][0], zz, 0,0,0); \
    acc1 = __builtin_amdgcn_mfma_f32_16x16x32_bf16(af1, whf[1][1], acc1, 0, 0, 0); \
    acc1 = __builtin_amdgcn_mfma_f32_16x16x32_bf16(af2, whf[1][2], acc1, 0, 0, 0); \
    acc1 = __builtin_amdgcn_mfma_f32_16x16x32_bf16(af3, whf[1][3], acc1, 0, 0, 0); \
    float ef = __builtin_amdgcn_exp2f(acc1[0] + gv[1]);                            \
    gxp += GXS;                                                                    \
    GN = gxp[og];                                                                  \
    /* gate 2 (g) */                                                               \
    f32x4 acc2 = __builtin_amdgcn_mfma_f32_16x16x32_bf16(af0, whf[2][0], zz, 0,0,0); \
    acc2 = __builtin_amdgcn_mfma_f32_16x16x32_bf16(af1, whf[2][1], acc2, 0, 0, 0); \
    acc2 = __builtin_amdgcn_mfma_f32_16x16x32_bf16(af2, whf[2][2], acc2, 0, 0, 0); \
    acc2 = __builtin_amdgcn_mfma_f32_16x16x32_bf16(af3, whf[2][3], acc2, 0, 0, 0); \
    float eg = __builtin_amdgcn_exp2f(acc2[0] + gv[2]);                            \
    /* gate 3 (o) */                                                               \
    f32x4 acc3 = __builtin_amdgcn_mfma_f32_16x16x32_bf16(af0, whf[3][0], zz, 0,0,0); \
    acc3 = __builtin_amdgcn_mfma_f32_16x16x32_bf16(af1, whf[3][1], acc3, 0, 0, 0); \
    acc3 = __builtin_amdgcn_mfma_f32_16x16x32_bf16(af2, whf[3][2], acc3, 0, 0, 0); \
    acc3 = __builtin_amdgcn_mfma_f32_16x16x32_bf16(af3, whf[3][3], acc3, 0, 0, 0); \
    float eo = __builtin_amdgcn_exp2f(acc3[0] + gv[3]);                            \
    /* combine: 7-trans common-denominator activation */                           \
    float ai = 1.0f + ei, av = 1.0f + ef, ag = 1.0f + eg, sg = 1.0f - eg;          \
    float pp = ai * ag;                                                            \
    float num = __builtin_fmaf(cs, pp, sg * av);                                   \
    float rd = __builtin_amdgcn_rcpf(av * pp);                                     \
    float cn = num * rd;                                                           \
    cs = cn;                                                                       \
    float ec = __builtin_amdgcn_exp2f(M2L2E * cn);                                 \
    float ao = 1.0f + eo, ac = 1.0f + ec, sc = 1.0f - ec;                          \
    float rd2 = __builtin_amdgcn_rcpf(ao * ac);                                    \
    float hv = sc * rd2;                                                           \
    unsigned int pk;                                                               \
    asm("v_cvt_pk_bf16_f32 %0, %1, %2" : "=v"(pk) : "v"(hv), "v"(hv));             \
    unsigned short hb = (unsigned short)pk;                                        \
    *(unsigned short*)((char*)(WR) + woff) = hb;                                   \
    if (LAYER == 0) {                                                              \
      outp_u[oidx] = hb;                                                           \
      outp_u += OUS;                                                               \
    } else {                                                                       \
      dp_u[didx] = hv;                                                             \
      dp_u += DPS;                                                                 \
    }                                                                              \
    asm volatile("s_waitcnt lgkmcnt(0)" ::: "memory");                             \
    __builtin_amdgcn_s_barrier();                                                  \
    asm volatile("" ::: "memory");                                                 \
  }

  for (int s = 0; s < T; s += 4) {
    STEP(hA, hB, ga, gb);
    STEP(hB, hA, gb, ga);
    STEP(hA, hB, ga, gb);
    STEP(hB, hA, gb, ga);
  }
#undef STEP

  if constexpr (LAYER == 1) {
    dout[XOUT + (size_t)b * 256 + dir * 128 + col] = cs;
  }
}

// ---------------------------------------------------------------------------
extern "C" void kernel_launch(void* const* d_in, const int* in_sizes, int n_in,
                              void* d_out, int out_size, void* d_ws, size_t ws_size,
                              hipStream_t stream) {
  const float* x    = (const float*)d_in[0];
  const float* wxf0 = (const float*)d_in[1];
  const float* whf0 = (const float*)d_in[2];
  const float* wxb0 = (const float*)d_in[3];
  const float* whb0 = (const float*)d_in[4];
  const float* wxf1 = (const float*)d_in[5];
  const float* whf1 = (const float*)d_in[6];
  const float* wxb1 = (const float*)d_in[7];
  const float* whb1 = (const float*)d_in[8];
  const float* bf0  = (const float*)d_in[9];
  const float* bb0  = (const float*)d_in[10];
  const float* bf1  = (const float*)d_in[11];
  const float* bb1  = (const float*)d_in[12];
  float* dout = (float*)d_out;

  // ws: [xp][out0 bf16][sw0][sw1][swh]
  const size_t needF32 = 268435456u + 33554432u + 262144u + 524288u + 524288u;
  bool xpf32 = ws_size >= needF32;
  size_t xpBytes = xpf32 ? 268435456u : 134217728u;
  unsigned char* ws = (unsigned char*)d_ws;
  void* xp = (void*)ws;
  unsigned short* out0 = (unsigned short*)(ws + xpBytes);
  unsigned short* sw0  = (unsigned short*)(ws + xpBytes + 33554432u);
  unsigned short* sw1  = sw0 + 2 * 65536;
  unsigned short* swh  = sw1 + 2 * 131072;

  prep_wx<<<1536, 256, 0, stream>>>(wxf0, wxb0, wxf1, wxb1, sw0, sw1);
  prep_wh<<<1024, 256, 0, stream>>>(whf0, whb0, whf1, whb1, swh);

  if (xpf32) {
    input_proj<0, true><<<dim3(2048, 2), 256, 0, stream>>>(x, nullptr, sw0, bf0, bb0, xp);
    lstm_scan<0, true><<<16, 512, 0, stream>>>(xp, swh, out0, dout);
    input_proj<1, true><<<dim3(2048, 2), 256, 0, stream>>>(nullptr, out0, sw1, bf1, bb1, xp);
    lstm_scan<1, true><<<16, 512, 0, stream>>>(xp, swh, out0, dout);
  } else {
    input_proj<0, false><<<dim3(2048, 2), 256, 0, stream>>>(x, nullptr, sw0, bf0, bb0, xp);
    lstm_scan<0, false><<<16, 512, 0, stream>>>(xp, swh, out0, dout);
    input_proj<1, false><<<dim3(2048, 2), 256, 0, stream>>>(nullptr, out0, sw1, bf1, bb1, xp);
    lstm_scan<1, false><<<16, 512, 0, stream>>>(xp, swh, out0, dout);
  }
}

// Round 11
// 1746.108 us; speedup vs baseline: 1.3103x; 1.0214x over previous
//
#include <hip/hip_runtime.h>
#include <hip/hip_bf16.h>
#include <stdint.h>
#include <type_traits>

// Bidirectional 2-layer LSTM, B=32, T=2048, F=H=128, G=4H=512.
// prep (Wx,Wh -> scaled bf16 frags) -> proj L0 -> scan L0 (16 WGs: dir x 8
// batch-octants of 4 rows) -> proj L1 -> scan L1. Gate pre-activations are
// pre-scaled by -log2e (i,f,o) / -2log2e (g) so sigmoid = rcp(1+exp2(y)).
// 7-trans common-denominator activation; 1 state elem per lane. Rows are
// duplicated CONSECUTIVELY (A row m = real row m>>2) so every acc reg of
// lane-group p equals real row p -> no select tree. Gate-major MFMA order.
// R11 = R7 + ASYMMETRIC wave-parity setprio: odd waves run s_setprio(2)
// across the MFMA cluster (scalar branch via readfirstlane so it is NOT
// exec-masked). Goal: stagger the two barrier-locked waves per SIMD so one
// wave's act VALU overlaps the other's MFMA pipe time (R7 counters show
// 506 cyc MFMA + 430 cyc VALU fully serialized, sum 98.5%, zero overlap).
// Ledger: R8 (gx->C-operand hand-schedule) -31%; R9 (SYMMETRIC setprio) -8%.

#define DEVINL __device__ __forceinline__

typedef __attribute__((ext_vector_type(8))) short short8;
typedef __attribute__((ext_vector_type(4))) float f32x4;

static constexpr int T = 2048;
static constexpr size_t XOUT = (size_t)32 * T * 256;
static constexpr float L2E = 1.4426950408889634f;
static constexpr float M2L2E = -2.8853900817779268f;

DEVINL unsigned short f2bf(float f) {
  unsigned int u = __float_as_uint(f);
  u += 0x7FFFu + ((u >> 16) & 1u);  // RNE
  return (unsigned short)(u >> 16);
}
DEVINL float gate_scale(int g) { return (g == 2) ? M2L2E : -L2E; }

// ---------------------------------------------------------------------------
// prep_wx: Wx (f32 [K][512]) -> scaled bf16 B-frags [dir][ng(32)][ks][lane][e8]
// ---------------------------------------------------------------------------
__global__ __launch_bounds__(256) void prep_wx(const float* wxf0, const float* wxb0,
                                               const float* wxf1, const float* wxb1,
                                               unsigned short* sw0, unsigned short* sw1) {
  int idx = blockIdx.x * 256 + threadIdx.x;
  if (idx < 2 * 65536) {                       // layer 0, KS=4
    int d = idx >> 16;
    int local = idx & 65535;
    const float* w = d ? wxb0 : wxf0;
    int e = local & 7, lane = (local >> 3) & 63, ks = (local >> 9) & 3, ng = local >> 11;
    int col = ng * 16 + (lane & 15);
    int k = ks * 32 + ((lane >> 4) << 3) + e;
    sw0[idx] = f2bf(w[k * 512 + col] * gate_scale(ng >> 3));
  } else {                                     // layer 1, KS=8
    int j = idx - 2 * 65536;
    if (j < 2 * 131072) {
      int d = j >> 17;
      int local = j & 131071;
      const float* w = d ? wxb1 : wxf1;
      int e = local & 7, lane = (local >> 3) & 63, ks = (local >> 9) & 7, ng = local >> 12;
      int col = ng * 16 + (lane & 15);
      int k = ks * 32 + ((lane >> 4) << 3) + e;
      sw1[j] = f2bf(w[k * 512 + col] * gate_scale(ng >> 3));
    }
  }
}

// ---------------------------------------------------------------------------
// prep_wh: Wh (f32 [128][512]) -> scaled bf16 frags, contiguous per wave:
// idx bits: e(0-2) lane(3-8) wid(9-11) ks(12-13) g(14-15) dir(16) layer(17)
// ---------------------------------------------------------------------------
__global__ __launch_bounds__(256) void prep_wh(const float* whf0, const float* whb0,
                                               const float* whf1, const float* whb1,
                                               unsigned short* swh) {
  int idx = blockIdx.x * 256 + threadIdx.x;
  if (idx >= 262144) return;
  int e = idx & 7, lane = (idx >> 3) & 63, wid = (idx >> 9) & 7;
  int ks = (idx >> 12) & 3, g = (idx >> 14) & 3, dir = (idx >> 16) & 1, layer = (idx >> 17) & 1;
  const float* w = layer ? (dir ? whb1 : whf1) : (dir ? whb0 : whf0);
  int col = g * 128 + wid * 16 + (lane & 15);
  int k = ks * 32 + ((lane >> 4) << 3) + e;
  swh[idx] = f2bf(w[k * 512 + col] * gate_scale(g));
}

// ---------------------------------------------------------------------------
// input_proj: xp[dir][t][q(8)][row(4)][col(128)][g(4)] = A(t)@Wx_scaled + b.
// Scan thread (q, row=p, col) then loads ONE float4/uint2 (4 gates).
// ---------------------------------------------------------------------------
template <int LAYER, bool XPF32>
__global__ __launch_bounds__(256) void input_proj(const float* x, const unsigned short* a_bf,
                                                  const unsigned short* wsw,
                                                  const float* bias_f, const float* bias_b,
                                                  void* xp_out) {
  constexpr int KS = (LAYER == 0) ? 4 : 8;
  int t = blockIdx.x, dir = blockIdx.y;
  int wid = threadIdx.x >> 6, lane = threadIdx.x & 63;   // wid = 0..3
  int p = lane >> 4, c15 = lane & 15;
  const unsigned short* wbase = wsw + (size_t)dir * (32 * KS * 64 * 8);
  const float* bias = dir ? bias_b : bias_f;

  short8 afrag[2][KS];
#pragma unroll
  for (int mt = 0; mt < 2; ++mt) {
#pragma unroll
    for (int ks = 0; ks < KS; ++ks) {
      int m = c15 + mt * 16;
      int kk = ks * 32 + (p << 3);
      if constexpr (LAYER == 0) {
        const float* ap = x + (size_t)m * (T * 128) + (size_t)t * 128 + kk;
        float4 lov = *(const float4*)ap;
        float4 hiv = *(const float4*)(ap + 4);
        short8 s;
        s[0] = (short)f2bf(lov.x); s[1] = (short)f2bf(lov.y);
        s[2] = (short)f2bf(lov.z); s[3] = (short)f2bf(lov.w);
        s[4] = (short)f2bf(hiv.x); s[5] = (short)f2bf(hiv.y);
        s[6] = (short)f2bf(hiv.z); s[7] = (short)f2bf(hiv.w);
        afrag[mt][ks] = s;
      } else {
        afrag[mt][ks] = *(const short8*)(a_bf + ((size_t)t * 32 + m) * 256 + kk);
      }
    }
  }

#pragma unroll
  for (int ngi = 0; ngi < 8; ++ngi) {
    int ng = wid * 8 + ngi;
    int g = ng >> 3, wd = ng & 7;
    f32x4 acc0 = {0.f, 0.f, 0.f, 0.f};
    f32x4 acc1 = {0.f, 0.f, 0.f, 0.f};
#pragma unroll
    for (int ks = 0; ks < KS; ++ks) {
      short8 b = *(const short8*)(wbase + ((size_t)(ng * KS + ks) * 64 + lane) * 8);
      acc0 = __builtin_amdgcn_mfma_f32_16x16x32_bf16(afrag[0][ks], b, acc0, 0, 0, 0);
      acc1 = __builtin_amdgcn_mfma_f32_16x16x32_bf16(afrag[1][ks], b, acc1, 0, 0, 0);
    }
    float bs = bias[ng * 16 + c15] * gate_scale(g);
    int gcol = wd * 16 + c15;
#pragma unroll
    for (int mt = 0; mt < 2; ++mt) {
      f32x4 v = (mt == 0) ? acc0 : acc1;
      v[0] += bs; v[1] += bs; v[2] += bs; v[3] += bs;
      // batch row = mt*16 + p*4 + r  ->  q = mt*4+p, rowInQ = r
      size_t base = (size_t)t * 16384 + (size_t)((mt * 4 + p) * 2048 + gcol * 4 + g);
      if constexpr (XPF32) {
        float* xpf = (float*)xp_out + (size_t)dir * ((size_t)T * 16384);
#pragma unroll
        for (int r = 0; r < 4; ++r) xpf[base + r * 512] = v[r];
      } else {
        unsigned short* xpb = (unsigned short*)xp_out + (size_t)dir * ((size_t)T * 16384);
#pragma unroll
        for (int r = 0; r < 4; ++r) xpb[base + r * 512] = f2bf(v[r]);
      }
    }
  }
}

// ---------------------------------------------------------------------------
// lstm_scan: 16 persistent WGs (blockIdx = dir*8 + octant q), 8 waves each.
// Wave wid owns 16 h-cols (all 4 gates) for 4 batch rows (consecutive-dup in
// the M-tile). Wh in regs; h double-buffered in LDS (4 x 288B, conflict-free);
// gx = one float4/uint2 per thread, prefetched 1 step ahead. 1 barrier/step.
// Odd waves elevate priority across the MFMA cluster (stagger vs even wave
// on the same SIMD so MFMA pipe and VALU overlap instead of serializing).
// ---------------------------------------------------------------------------
DEVINL f32x4 gx2v(float4 v) { f32x4 r; r[0]=v.x; r[1]=v.y; r[2]=v.z; r[3]=v.w; return r; }
DEVINL f32x4 gx2v(uint2 u) {
  f32x4 r;
  r[0] = __uint_as_float(u.x << 16);
  r[1] = __uint_as_float(u.x & 0xFFFF0000u);
  r[2] = __uint_as_float(u.y << 16);
  r[3] = __uint_as_float(u.y & 0xFFFF0000u);
  return r;
}

template <int LAYER, bool XPF32>
__global__ __launch_bounds__(512) void lstm_scan(const void* xp, const unsigned short* swh,
                                                 unsigned short* out0, float* dout) {
  using gxT = typename std::conditional<XPF32, float4, uint2>::type;
  int dir = blockIdx.x >> 3;
  int q = blockIdx.x & 7;
  int wid = threadIdx.x >> 6, lane = threadIdx.x & 63;
  int c15 = lane & 15, p = lane >> 4;
  int col = wid * 16 + c15;

  // wave-parity priority flag in an SGPR (scalar branch, NOT exec-masked:
  // s_setprio ignores exec, so an exec-mask "if" would apply to all waves)
  const int hiprio = __builtin_amdgcn_readfirstlane(wid) & 1;

  __shared__ __align__(16) unsigned char hA[1280];  // 4 rows x 288B (128 bf16 + pad)
  __shared__ __align__(16) unsigned char hB[1280];

  // Wh fragments (pre-scaled, pre-fragged): 16 contiguous b128 loads
  const unsigned short* whbase = swh + (size_t)LAYER * 131072 + (size_t)dir * 65536;
  short8 whf[4][4];
#pragma unroll
  for (int g = 0; g < 4; ++g)
#pragma unroll
    for (int ks = 0; ks < 4; ++ks)
      whf[g][ks] = *(const short8*)(whbase + g * 16384 + ks * 4096 + wid * 512 + lane * 8);

  if (threadIdx.x < 288) {
    ((unsigned int*)hA)[threadIdx.x] = 0u;
    ((unsigned int*)hB)[threadIdx.x] = 0u;
  }

  // A-frag read offsets: A row m = lane&15 holds real row m>>2 (consecutive dup)
  int aoff[4];
#pragma unroll
  for (int ks = 0; ks < 4; ++ks)
    aoff[ks] = ((lane & 15) >> 2) * 288 + ((lane >> 4) << 4) + ks * 64;
  // h write offset: row p, col
  int woff = p * 288 + col * 2;

  // gx: one gxT per thread per step (uniform base, constant lane index)
  const gxT* gxp = (const gxT*)xp + (size_t)dir * ((size_t)T * 4096);
  int og = q * 512 + p * 128 + col;

  int b = q * 4 + p;                                   // global batch row
  float cs = 0.f;

  int t0 = dir ? (T - 1) : 0;
  int ts = dir ? -1 : 1;

  gxp += (size_t)t0 * 4096;
  // uniform store bases + constant 32-bit lane indices (saddr-form stores)
  unsigned short* outp_u = out0 + (size_t)t0 * 8192;
  float* dp_u = dout + (size_t)t0 * 256;
  unsigned int oidx = (unsigned int)(b * 256 + dir * 128 + col);
  unsigned int didx = (unsigned int)((size_t)b * T * 256 + dir * 128 + col);
  const ptrdiff_t GXS = (ptrdiff_t)ts * 4096;
  const ptrdiff_t OUS = (ptrdiff_t)ts * 8192;
  const ptrdiff_t DPS = (ptrdiff_t)ts * 256;

  gxT ga = gxp[og];
  gxT gb;
  __syncthreads();

#define STEP(RD, WR, GC, GN)                                                       \
  {                                                                                \
    short8 af0 = *(const short8*)((const char*)(RD) + aoff[0]);                    \
    short8 af1 = *(const short8*)((const char*)(RD) + aoff[1]);                    \
    short8 af2 = *(const short8*)((const char*)(RD) + aoff[2]);                    \
    short8 af3 = *(const short8*)((const char*)(RD) + aoff[3]);                    \
    const f32x4 zz = {0.f, 0.f, 0.f, 0.f};                                         \
    f32x4 gv = gx2v(GC);                                                           \
    if (hiprio) __builtin_amdgcn_s_setprio(2);                                     \
    /* gate 0 (i) */                                                               \
    f32x4 acc0 = __builtin_amdgcn_mfma_f32_16x16x32_bf16(af0, whf[0][0], zz, 0,0,0); \
    acc0 = __builtin_amdgcn_mfma_f32_16x16x32_bf16(af1, whf[0][1], acc0, 0, 0, 0); \
    acc0 = __builtin_amdgcn_mfma_f32_16x16x32_bf16(af2, whf[0][2], acc0, 0, 0, 0); \
    acc0 = __builtin_amdgcn_mfma_f32_16x16x32_bf16(af3, whf[0][3], acc0, 0, 0, 0); \
    float ei = __builtin_amdgcn_exp2f(acc0[0] + gv[0]);                            \
    /* gate 1 (f) */                                                               \
    f32x4 acc1 = __builtin_amdgcn_mfma_f32_16x16x32_bf16(af0, whf[1][0], zz, 0,0,0); \
    acc1 = __builtin_amdgcn_mfma_f32_16x16x32_bf16(af1, whf[1][1], acc1, 0, 0, 0); \
    acc1 = __builtin_amdgcn_mfma_f32_16x16x32_bf16(af2, whf[1][2], acc1, 0, 0, 0); \
    acc1 = __builtin_amdgcn_mfma_f32_16x16x32_bf16(af3, whf[1][3], acc1, 0, 0, 0); \
    float ef = __builtin_amdgcn_exp2f(acc1[0] + gv[1]);                            \
    gxp += GXS;                                                                    \
    GN = gxp[og];                                                                  \
    /* gate 2 (g) */                                                               \
    f32x4 acc2 = __builtin_amdgcn_mfma_f32_16x16x32_bf16(af0, whf[2][0], zz, 0,0,0); \
    acc2 = __builtin_amdgcn_mfma_f32_16x16x32_bf16(af1, whf[2][1], acc2, 0, 0, 0); \
    acc2 = __builtin_amdgcn_mfma_f32_16x16x32_bf16(af2, whf[2][2], acc2, 0, 0, 0); \
    acc2 = __builtin_amdgcn_mfma_f32_16x16x32_bf16(af3, whf[2][3], acc2, 0, 0, 0); \
    float eg = __builtin_amdgcn_exp2f(acc2[0] + gv[2]);                            \
    /* gate 3 (o) */                                                               \
    f32x4 acc3 = __builtin_amdgcn_mfma_f32_16x16x32_bf16(af0, whf[3][0], zz, 0,0,0); \
    acc3 = __builtin_amdgcn_mfma_f32_16x16x32_bf16(af1, whf[3][1], acc3, 0, 0, 0); \
    acc3 = __builtin_amdgcn_mfma_f32_16x16x32_bf16(af2, whf[3][2], acc3, 0, 0, 0); \
    acc3 = __builtin_amdgcn_mfma_f32_16x16x32_bf16(af3, whf[3][3], acc3, 0, 0, 0); \
    if (hiprio) __builtin_amdgcn_s_setprio(0);                                     \
    float eo = __builtin_amdgcn_exp2f(acc3[0] + gv[3]);                            \
    /* combine: 7-trans common-denominator activation */                           \
    float ai = 1.0f + ei, av = 1.0f + ef, ag = 1.0f + eg, sg = 1.0f - eg;          \
    float pp = ai * ag;                                                            \
    float num = __builtin_fmaf(cs, pp, sg * av);                                   \
    float rd = __builtin_amdgcn_rcpf(av * pp);                                     \
    float cn = num * rd;                                                           \
    cs = cn;                                                                       \
    float ec = __builtin_amdgcn_exp2f(M2L2E * cn);                                 \
    float ao = 1.0f + eo, ac = 1.0f + ec, sc = 1.0f - ec;                          \
    float rd2 = __builtin_amdgcn_rcpf(ao * ac);                                    \
    float hv = sc * rd2;                                                           \
    unsigned int pk;                                                               \
    asm("v_cvt_pk_bf16_f32 %0, %1, %2" : "=v"(pk) : "v"(hv), "v"(hv));             \
    unsigned short hb = (unsigned short)pk;                                        \
    *(unsigned short*)((char*)(WR) + woff) = hb;                                   \
    if (LAYER == 0) {                                                              \
      outp_u[oidx] = hb;                                                           \
      outp_u += OUS;                                                               \
    } else {                                                                       \
      dp_u[didx] = hv;                                                             \
      dp_u += DPS;                                                                 \
    }                                                                              \
    asm volatile("s_waitcnt lgkmcnt(0)" ::: "memory");                             \
    __builtin_amdgcn_s_barrier();                                                  \
    asm volatile("" ::: "memory");                                                 \
  }

  for (int s = 0; s < T; s += 4) {
    STEP(hA, hB, ga, gb);
    STEP(hB, hA, gb, ga);
    STEP(hA, hB, ga, gb);
    STEP(hB, hA, gb, ga);
  }
#undef STEP

  if constexpr (LAYER == 1) {
    dout[XOUT + (size_t)b * 256 + dir * 128 + col] = cs;
  }
}

// ---------------------------------------------------------------------------
extern "C" void kernel_launch(void* const* d_in, const int* in_sizes, int n_in,
                              void* d_out, int out_size, void* d_ws, size_t ws_size,
                              hipStream_t stream) {
  const float* x    = (const float*)d_in[0];
  const float* wxf0 = (const float*)d_in[1];
  const float* whf0 = (const float*)d_in[2];
  const float* wxb0 = (const float*)d_in[3];
  const float* whb0 = (const float*)d_in[4];
  const float* wxf1 = (const float*)d_in[5];
  const float* whf1 = (const float*)d_in[6];
  const float* wxb1 = (const float*)d_in[7];
  const float* whb1 = (const float*)d_in[8];
  const float* bf0  = (const float*)d_in[9];
  const float* bb0  = (const float*)d_in[10];
  const float* bf1  = (const float*)d_in[11];
  const float* bb1  = (const float*)d_in[12];
  float* dout = (float*)d_out;

  // ws: [xp][out0 bf16][sw0][sw1][swh]
  const size_t needF32 = 268435456u + 33554432u + 262144u + 524288u + 524288u;
  bool xpf32 = ws_size >= needF32;
  size_t xpBytes = xpf32 ? 268435456u : 134217728u;
  unsigned char* ws = (unsigned char*)d_ws;
  void* xp = (void*)ws;
  unsigned short* out0 = (unsigned short*)(ws + xpBytes);
  unsigned short* sw0  = (unsigned short*)(ws + xpBytes + 33554432u);
  unsigned short* sw1  = sw0 + 2 * 65536;
  unsigned short* swh  = sw1 + 2 * 131072;

  prep_wx<<<1536, 256, 0, stream>>>(wxf0, wxb0, wxf1, wxb1, sw0, sw1);
  prep_wh<<<1024, 256, 0, stream>>>(whf0, whb0, whf1, whb1, swh);

  if (xpf32) {
    input_proj<0, true><<<dim3(2048, 2), 256, 0, stream>>>(x, nullptr, sw0, bf0, bb0, xp);
    lstm_scan<0, true><<<16, 512, 0, stream>>>(xp, swh, out0, dout);
    input_proj<1, true><<<dim3(2048, 2), 256, 0, stream>>>(nullptr, out0, sw1, bf1, bb1, xp);
    lstm_scan<1, true><<<16, 512, 0, stream>>>(xp, swh, out0, dout);
  } else {
    input_proj<0, false><<<dim3(2048, 2), 256, 0, stream>>>(x, nullptr, sw0, bf0, bb0, xp);
    lstm_scan<0, false><<<16, 512, 0, stream>>>(xp, swh, out0, dout);
    input_proj<1, false><<<dim3(2048, 2), 256, 0, stream>>>(nullptr, out0, sw1, bf1, bb1, xp);
    lstm_scan<1, false><<<16, 512, 0, stream>>>(xp, swh, out0, dout);
  }
}